// Round 2
// baseline (206.860 us; speedup 1.0000x reference)
//
#include <hip/hip_runtime.h>

#define NL 30

typedef float f32x2 __attribute__((ext_vector_type(2)));

static __device__ __forceinline__ f32x2 splat2(float v) { return (f32x2){v, v}; }

__global__ __launch_bounds__(256) void drn_kernel(
    const float* __restrict__ x1, const float* __restrict__ x2,
    const float* __restrict__ W1, const float* __restrict__ b1,
    const float* __restrict__ W2,
    float* __restrict__ o1, float* __restrict__ o2, int nrows)
{
    long t = (long)blockIdx.x * blockDim.x + threadIdx.x;
    long row0 = t * 4;
    if (row0 >= nrows) return;

    // Load 4 rows. x1: one float4. x2: 20 contiguous floats = 5 float4
    // (80B offset per thread -> 16B aligned).
    float4 h1v = *(const float4*)(x1 + row0);
    float xs[20];
    {
        const float4* px2 = (const float4*)(x2 + row0 * 5);
        #pragma unroll
        for (int i = 0; i < 5; ++i) ((float4*)xs)[i] = px2[i];
    }

    // Repack into row-pairs: h2[j][p] = {row(2p) elem j, row(2p+1) elem j}
    // so all math is <2 x float> -> v_pk_fma_f32 / v_pk_max_f32.
    f32x2 h1p[2] = { (f32x2){h1v.x, h1v.y}, (f32x2){h1v.z, h1v.w} };
    f32x2 h2[5][2];
    #pragma unroll
    for (int j = 0; j < 5; ++j) {
        h2[j][0] = (f32x2){xs[0 * 5 + j], xs[1 * 5 + j]};
        h2[j][1] = (f32x2){xs[2 * 5 + j], xs[3 * 5 + j]};
    }

    const f32x2 zero = splat2(0.0f);

    // Params are wave-uniform -> scalar loads (SGPRs), no LDS, no VGPR cost.
    for (int l = 0; l < NL; ++l) {
        float w1r[5], w2r[5];
        #pragma unroll
        for (int j = 0; j < 5; ++j) w1r[j] = W1[l * 5 + j];
        float bb = b1[l];
        #pragma unroll
        for (int j = 0; j < 5; ++j) w2r[j] = W2[l * 5 + j];

        #pragma unroll
        for (int p = 0; p < 2; ++p) {
            f32x2 s = h1p[p] + splat2(bb);
            #pragma unroll
            for (int j = 0; j < 5; ++j)
                s += __builtin_elementwise_max(h2[j][p], zero) * splat2(w1r[j]);
            h1p[p] = s;
            f32x2 rh = __builtin_elementwise_max(s, zero);
            #pragma unroll
            for (int j = 0; j < 5; ++j)
                h2[j][p] += rh * splat2(w2r[j]);
        }
    }

    // Repack to row-major and store.
    float ys[20];
    #pragma unroll
    for (int j = 0; j < 5; ++j) {
        ys[0 * 5 + j] = h2[j][0].x;
        ys[1 * 5 + j] = h2[j][0].y;
        ys[2 * 5 + j] = h2[j][1].x;
        ys[3 * 5 + j] = h2[j][1].y;
    }

    *(float4*)(o1 + row0) = make_float4(h1p[0].x, h1p[0].y, h1p[1].x, h1p[1].y);
    float4* po2 = (float4*)(o2 + row0 * 5);
    #pragma unroll
    for (int i = 0; i < 5; ++i) po2[i] = ((float4*)ys)[i];
}

extern "C" void kernel_launch(void* const* d_in, const int* in_sizes, int n_in,
                              void* d_out, int out_size, void* d_ws, size_t ws_size,
                              hipStream_t stream) {
    const float* x1 = (const float*)d_in[0];
    const float* x2 = (const float*)d_in[1];
    const float* W1 = (const float*)d_in[2];
    const float* b1 = (const float*)d_in[3];
    const float* W2 = (const float*)d_in[4];
    int nrows = in_sizes[0];            // 4,194,304
    float* o1 = (float*)d_out;          // [nrows]
    float* o2 = (float*)d_out + nrows;  // [nrows*5]

    int nthreads = nrows / 4;           // 4 rows per thread
    int block = 256;
    int grid = (nthreads + block - 1) / block;
    drn_kernel<<<grid, block, 0, stream>>>(x1, x2, W1, b1, W2, o1, o2, nrows);
}